// Round 13
// baseline (370.862 us; speedup 1.0000x reference)
//
#include <hip/hip_runtime.h>

// out[b,co,h,w] = sum_ci dq( conv3x3(x[b,ci], W[ci,co]) + b[ci,co] )
// Bit-exactness contract (verified R3 absmax==0, R4..R12 = 1.430511e-6):
//   per-pixel conv = sequential fmaf over k=(kh*3+kw) ascending, seeded from 0;
//   bias after as plain f32 add; t = y * (float)(15/9); rintf (half-even);
//   dequant+sum: fmaf(q, 0.6f, acc), ci ascending. __shfl moves exact bits.
// R13: RESTRUCTURE away from the LDS-tile+barrier+per-ci-lgkm-drain family
// (R6..R12 all plateau at ~27us kernel vs ~11us VALU-busy: the invariant
// stall is the lockstep barrier/lgkm shape itself). New shape:
//   - wave = 64 consecutive columns (2 col-spans cover W=112, overlap masked)
//   - thread = 1 col x 2 output rows; per ci: 4 coalesced global row-loads
//     (x now ticks vmcnt ONLY - decoupled from weight SMEM lgkm), +-1-col
//     taps via __shfl from neighbor lanes, scalar fma with SGPR weights.
//   - no __shared__, no barrier; waves fully independent and de-phased.

constexpr int B_    = 8;
constexpr int CIN   = 16;
constexpr int COUT  = 32;
constexpr int H_    = 112;
constexpr int W_    = 112;
constexpr int COG   = 8;             // co per wave (4 waves cover 32)
constexpr int RB    = 2;             // output rows per thread

__global__ __launch_bounds__(256, 4)
void conv_quant_sum_kernel(const float* __restrict__ x,
                           const float* __restrict__ w,
                           const float* __restrict__ bias,
                           float* __restrict__ out)
{
#pragma clang fp contract(off)
    const float QS = (float)(15.0 / 9.0);   // 1.66666663f
    const float DQ = 0.6f;                  // post-round dequant multiplier

    const int t    = threadIdx.x;
    const int l    = t & 63;
    const int wid  = __builtin_amdgcn_readfirstlane(t >> 6);
    const int cog  = wid * COG;

    const int span = blockIdx.x;            // 0: cols -1..62, 1: cols 49..112
    const int x0   = span ? 49 : -1;
    const int r0   = blockIdx.y * RB;       // output rows r0, r0+1
    const int b    = blockIdx.z;

    const int c    = x0 + l;                // this lane's loaded column
    const bool cin = (unsigned)c < (unsigned)W_;

    const float* xb = x + (size_t)b * CIN * H_ * W_;

    float acc[RB][COG];
#pragma unroll
    for (int r = 0; r < RB; ++r)
#pragma unroll
        for (int co = 0; co < COG; ++co) acc[r][co] = 0.0f;

#pragma unroll
    for (int ci = 0; ci < CIN; ++ci) {
        // 4 halo rows r0-1 .. r0+2, one coalesced dword per lane each
        float xm[4];     // mid (own column)
#pragma unroll
        for (int j = 0; j < 4; ++j) {
            const int gh  = r0 - 1 + j;
            const bool in = cin && ((unsigned)gh < (unsigned)H_);
            const float* p = xb + ci * (H_ * W_) + (in ? gh * W_ + c : 0);
            float v = *p;                   // safe address when OOB
            xm[j] = in ? v : 0.0f;          // zero padding
        }
        float xl[4], xr[4];                 // exact-bit lane shifts
#pragma unroll
        for (int j = 0; j < 4; ++j) {
            xl[j] = __shfl(xm[j], l - 1, 64);   // col c-1 (lane0 garbage: masked)
            xr[j] = __shfl(xm[j], l + 1, 64);   // col c+1 (lane63 garbage: masked)
        }

        const float* wc = w + (ci * COUT + cog) * 9;   // wave-uniform scalar
        const float* bc = bias + ci * COUT + cog;
#pragma unroll
        for (int co = 0; co < COG; ++co) {
#pragma unroll
            for (int r = 0; r < RB; ++r) {
                float s = 0.0f;                        // conv seeded from 0
#pragma unroll
                for (int kh = 0; kh < 3; ++kh) {       // k ascending
                    s = fmaf(xl[r + kh], wc[co * 9 + kh * 3 + 0], s);
                    s = fmaf(xm[r + kh], wc[co * 9 + kh * 3 + 1], s);
                    s = fmaf(xr[r + kh], wc[co * 9 + kh * 3 + 2], s);
                }
                float y = s + bc[co];                  // bias: separate add
                float q = rintf(y * QS);               // half-even
                acc[r][co] = fmaf(q, DQ, acc[r][co]);  // post-round dequant
            }
        }
    }

    // ---- masked store: span0 owns cols 0..61, span1 owns 62..111 ----
    const bool valid = span ? (l >= 13 && l <= 62) : (l >= 1 && l <= 62);
    if (valid) {
        float* ob = out + ((size_t)b * COUT + cog) * H_ * W_;
#pragma unroll
        for (int co = 0; co < COG; ++co)
#pragma unroll
            for (int r = 0; r < RB; ++r)
                ob[co * H_ * W_ + (r0 + r) * W_ + c] = acc[r][co];
    }
}

extern "C" void kernel_launch(void* const* d_in, const int* in_sizes, int n_in,
                              void* d_out, int out_size, void* d_ws, size_t ws_size,
                              hipStream_t stream)
{
    const float* x    = (const float*)d_in[0];
    const float* w    = (const float*)d_in[1];
    const float* bias = (const float*)d_in[2];
    float* out        = (float*)d_out;

    dim3 grid(2, H_ / RB, B_);   // (2, 56, 8) = 896 blocks, no barrier, no LDS
    dim3 block(256);
    conv_quant_sum_kernel<<<grid, block, 0, stream>>>(x, w, bias, out);
}

// Round 14
// 85.187 us; speedup vs baseline: 4.3535x; 4.3535x over previous
//
#include <hip/hip_runtime.h>

// out[b,co,h,w] = sum_ci dq( conv3x3(x[b,ci], W[ci,co]) + b[ci,co] )
// Bit-exactness contract (verified R3 absmax==0, R4..R13 = 1.430511e-6):
//   per-pixel conv = sequential fma over k=(kh*3+kw) ascending, seeded from 0;
//   bias after as plain f32 add; t = y * (float)(15/9); rintf (half-even);
//   dequant+sum: fma(q, 0.6f, acc), ci ascending. v_pk_fma_f32 is IEEE per
//   32-bit half; weights pass through LDS bit-unchanged.
// R14 = R12 structure + ZERO SMEM IN THE K-LOOP. Mechanism: SMEM (s_load)
// returns out-of-order -> every use forces s_waitcnt lgkmcnt(0), draining all
// pending DS reads too -> 16 unpipelineable ~200cyc drains/wave (explains
// R7's neutral unroll). Weights+bias for this block's 16 co staged into LDS
// in the prologue; inner-loop weight reads are wave-uniform ds_read
// broadcasts (single-bank). DS is IN-ORDER -> compiler can emit partial
// lgkmcnt(N) waits and software-pipeline the unrolled ci loop.

typedef float v2f __attribute__((ext_vector_type(2)));

constexpr int B_    = 8;
constexpr int CIN   = 16;
constexpr int COUT  = 32;
constexpr int H_    = 112;
constexpr int W_    = 112;
constexpr int TW    = 16;            // tile width  (112 = 7*16)
constexpr int TH    = 16;            // tile height (112 = 7*16)
constexpr int HH_   = TH + 2;        // halo rows 18
constexpr int LDSW  = 22;            // even (b64) + conflict-free ty stride
constexpr int COG   = 4;             // co per wave; block covers 16 co

__global__ __launch_bounds__(256, 4)
void conv_quant_sum_kernel(const float* __restrict__ x,
                           const float* __restrict__ w,
                           const float* __restrict__ bias,
                           float* __restrict__ out)
{
#pragma clang fp contract(off)
    const float QS = (float)(15.0 / 9.0);   // 1.66666663f
    const float DQ = 0.6f;                  // post-round dequant multiplier

    __shared__ float xs[CIN][HH_][LDSW];    // 16*18*22*4 = 25.3 KB
    __shared__ float wl[CIN][16][12];       // 9 used, pad 12 (48B: b128-aligned per co)
    __shared__ float bl[CIN][16];           // 1 KB          -> total 37.8 KB

    const int t    = threadIdx.x;
    const int lane = t & 63;
    const int tx   = lane & 7;              // pair col: pixels 2tx, 2tx+1
    const int ty2  = lane >> 3;             // row-pair 0..7
    const int wid  = __builtin_amdgcn_readfirstlane(t >> 6);

    const int tile_x = blockIdx.x * TW;
    const int tile_y = blockIdx.y * TH;
    const int b      = blockIdx.z >> 1;
    const int cog0   = (blockIdx.z & 1) * 16;   // block's 16-co base

    // ---- prologue A: weights+bias for cog0..cog0+15 into LDS ----
    {
#pragma unroll
        for (int j = 0; j < 9; ++j) {           // 2304 dwords, coalesced
            int idx = j * 256 + t;
            int ci  = idx / 144;                // 144 = 16co * 9
            int rem = idx - ci * 144;
            int co  = rem / 9;
            int k   = rem - co * 9;
            wl[ci][co][k] = w[(ci * COUT + cog0 + co) * 9 + k];
        }
        bl[t >> 4][t & 15] = bias[(t >> 4) * COUT + cog0 + (t & 15)];
    }

    // ---- prologue B: x halo (18 rows x 20 cols per ci), latency-batched ----
    const float* xb = x + (size_t)b * CIN * H_ * W_;
    {
        const int sr0 = t / 20,  sc0 = t - sr0 * 20;
        const int i1  = t + 256;
        const int sr1 = i1 / 20, sc1 = i1 - sr1 * 20;
        const bool a1 = (sr1 < HH_);
        const int gh0 = tile_y + sr0 - 1, gw0 = tile_x + sc0 - 1;
        const int gh1 = tile_y + sr1 - 1, gw1 = tile_x + sc1 - 1;
        const bool in0 = ((unsigned)gh0 < (unsigned)H_) && ((unsigned)gw0 < (unsigned)W_);
        const bool in1 = a1 && ((unsigned)gh1 < (unsigned)H_) && ((unsigned)gw1 < (unsigned)W_);
        const float* sp0 = in0 ? (xb + gh0 * W_ + gw0) : xb;
        const float* sp1 = in1 ? (xb + gh1 * W_ + gw1) : xb;
        float v0[CIN], v1[CIN];
#pragma unroll
        for (int ci = 0; ci < CIN; ++ci) { v0[ci] = sp0[ci * (H_ * W_)];
                                           v1[ci] = sp1[ci * (H_ * W_)]; }
#pragma unroll
        for (int ci = 0; ci < CIN; ++ci) { v0[ci] = in0 ? v0[ci] : 0.0f;
                                           v1[ci] = in1 ? v1[ci] : 0.0f; }
#pragma unroll
        for (int ci = 0; ci < CIN; ++ci) xs[ci][sr0][sc0] = v0[ci];
        if (a1) {
#pragma unroll
            for (int ci = 0; ci < CIN; ++ci) xs[ci][sr1][sc1] = v1[ci];
        }
    }
    __syncthreads();

    v2f acc[COG][2];
#pragma unroll
    for (int co = 0; co < COG; ++co) {
        acc[co][0] = v2f{0.0f, 0.0f};
        acc[co][1] = v2f{0.0f, 0.0f};
    }

#pragma unroll
    for (int ci = 0; ci < CIN; ++ci) {
        // 4 halo rows 2ty2..2ty2+3 feed output rows 2ty2, 2ty2+1
        v2f xw[4][3];
#pragma unroll
        for (int r = 0; r < 4; ++r) {
            const float* row = &xs[ci][2 * ty2 + r][2 * tx];
            v2f p0 = *reinterpret_cast<const v2f*>(row);
            v2f p1 = *reinterpret_cast<const v2f*>(row + 2);
            xw[r][0] = p0;
            xw[r][1] = v2f{p0.y, p1.x};
            xw[r][2] = p1;
        }

        // wave-uniform LDS broadcasts (DS = in-order -> partial lgkm waits)
        const float* wc = &wl[ci][wid * COG][0];
        const float* bc = &bl[ci][wid * COG];
#pragma unroll
        for (int co = 0; co < COG; ++co) {
            v2f s0 = v2f{0.0f, 0.0f};
            v2f s1 = v2f{0.0f, 0.0f};
#pragma unroll
            for (int k = 0; k < 9; ++k) {              // k ascending per pixel
                float wv = wc[co * 12 + k];
                v2f wvv = v2f{wv, wv};
                s0 = __builtin_elementwise_fma(xw[k / 3][k % 3],     wvv, s0);
                s1 = __builtin_elementwise_fma(xw[k / 3 + 1][k % 3], wvv, s1);
            }
            float bv = bc[co];
            v2f bvv = v2f{bv, bv};
            v2f y0 = s0 + bvv, y1 = s1 + bvv;          // bias: pk_add
            v2f t0 = y0 * v2f{QS, QS}, t1 = y1 * v2f{QS, QS};
            v2f q0, q1;
            q0.x = rintf(t0.x); q0.y = rintf(t0.y);    // half-even
            q1.x = rintf(t1.x); q1.y = rintf(t1.y);
            acc[co][0] = __builtin_elementwise_fma(q0, v2f{DQ, DQ}, acc[co][0]);
            acc[co][1] = __builtin_elementwise_fma(q1, v2f{DQ, DQ}, acc[co][1]);
        }
    }

    // ---- store: 2 rows x 2 cols per thread, b64 each ----
    float* ob = out + ((size_t)b * COUT + cog0 + wid * COG) * H_ * W_;
    const int oh = tile_y + 2 * ty2;
    const int ow = tile_x + 2 * tx;
#pragma unroll
    for (int co = 0; co < COG; ++co) {
        *reinterpret_cast<v2f*>(ob + co * H_ * W_ + oh * W_ + ow)       = acc[co][0];
        *reinterpret_cast<v2f*>(ob + co * H_ * W_ + (oh + 1) * W_ + ow) = acc[co][1];
    }
}

extern "C" void kernel_launch(void* const* d_in, const int* in_sizes, int n_in,
                              void* d_out, int out_size, void* d_ws, size_t ws_size,
                              hipStream_t stream)
{
    const float* x    = (const float*)d_in[0];
    const float* w    = (const float*)d_in[1];
    const float* bias = (const float*)d_in[2];
    float* out        = (float*)d_out;

    dim3 grid(W_ / TW, H_ / TH, B_ * 2);   // (7, 7, 16) = 784 blocks
    dim3 block(256);
    conv_quant_sum_kernel<<<grid, block, 0, stream>>>(x, w, bias, out);
}

// Round 15
// 83.408 us; speedup vs baseline: 4.4464x; 1.0213x over previous
//
#include <hip/hip_runtime.h>

// out[b,co,h,w] = sum_ci dq( conv3x3(x[b,ci], W[ci,co]) + b[ci,co] )
// Bit-exactness contract (verified R3 absmax==0, R4..R14 = 1.430511e-6):
//   per-pixel conv = sequential fma over k=(kh*3+kw) ascending, seeded from 0;
//   bias after as plain f32 add; t = y * (float)(15/9); rintf (half-even);
//   dequant+sum: fma(q, 0.6f, acc), ci ascending. v_pk_fma_f32 is IEEE per
//   32-bit half -> identical bits per pixel.
// R15: raise MATH DENSITY (VALU busy-time ~18-20us is the measured dominant
// term; all stall levers R7-R14 were neutral). COG=8 with 2x2 px/thread:
// one wave covers the whole 16x16 tile, 4 waves = all 32 co -> per-ci
// non-math overhead (8 ds_read_b64 + window movs) amortized over 2x the
// pk-math, and ONE staging serves all 32 co (no co-split duplication).
// Grid (7,7,8)=392 - same 30% makespan-tail class as every prior round, so
// the density delta is isolated. launch_bounds(256,2): 256-VGPR budget so
// acc[8][2]+xw[4][3] don't spill (residency is grid-capped anyway; R8/R9
// proved occupancy non-binding).

typedef float v2f __attribute__((ext_vector_type(2)));

constexpr int B_    = 8;
constexpr int CIN   = 16;
constexpr int COUT  = 32;
constexpr int H_    = 112;
constexpr int W_    = 112;
constexpr int TW    = 16;            // tile width  (112 = 7*16)
constexpr int TH    = 16;            // tile height (112 = 7*16)
constexpr int HH_   = TH + 2;        // halo rows 18
constexpr int LDSW  = 22;            // even (b64) + distinct ty2 bank offsets
constexpr int COG   = 8;             // co per wave; 4 waves = all 32 co

__global__ __launch_bounds__(256, 2)
void conv_quant_sum_kernel(const float* __restrict__ x,
                           const float* __restrict__ w,
                           const float* __restrict__ bias,
                           float* __restrict__ out)
{
#pragma clang fp contract(off)
    const float QS = (float)(15.0 / 9.0);   // 1.66666663f
    const float DQ = 0.6f;                  // post-round dequant multiplier

    __shared__ float xs[CIN][HH_][LDSW];    // 16*18*22*4 = 25.3 KB

    const int t    = threadIdx.x;
    const int lane = t & 63;
    const int tx   = lane & 7;              // pair col: pixels 2tx, 2tx+1
    const int ty2  = lane >> 3;             // pair row: rows 2ty2, 2ty2+1
    const int wid  = __builtin_amdgcn_readfirstlane(t >> 6);
    const int cog  = wid * COG;             // 0,8,16,24

    const int tile_x = blockIdx.x * TW;
    const int tile_y = blockIdx.y * TH;
    const int b      = blockIdx.z;

    // ---- stage x halo (18 rows x 20 cols per ci), latency-batched ----
    const float* xb = x + (size_t)b * CIN * H_ * W_;
    {
        const int sr0 = t / 20,  sc0 = t - sr0 * 20;
        const int i1  = t + 256;
        const int sr1 = i1 / 20, sc1 = i1 - sr1 * 20;
        const bool a1 = (sr1 < HH_);
        const int gh0 = tile_y + sr0 - 1, gw0 = tile_x + sc0 - 1;
        const int gh1 = tile_y + sr1 - 1, gw1 = tile_x + sc1 - 1;
        const bool in0 = ((unsigned)gh0 < (unsigned)H_) && ((unsigned)gw0 < (unsigned)W_);
        const bool in1 = a1 && ((unsigned)gh1 < (unsigned)H_) && ((unsigned)gw1 < (unsigned)W_);
        const float* sp0 = in0 ? (xb + gh0 * W_ + gw0) : xb;
        const float* sp1 = in1 ? (xb + gh1 * W_ + gw1) : xb;
        float v0[CIN], v1[CIN];
#pragma unroll
        for (int ci = 0; ci < CIN; ++ci) { v0[ci] = sp0[ci * (H_ * W_)];
                                           v1[ci] = sp1[ci * (H_ * W_)]; }
#pragma unroll
        for (int ci = 0; ci < CIN; ++ci) { v0[ci] = in0 ? v0[ci] : 0.0f;
                                           v1[ci] = in1 ? v1[ci] : 0.0f; }
#pragma unroll
        for (int ci = 0; ci < CIN; ++ci) xs[ci][sr0][sc0] = v0[ci];
        if (a1) {
#pragma unroll
            for (int ci = 0; ci < CIN; ++ci) xs[ci][sr1][sc1] = v1[ci];
        }
    }
    __syncthreads();

    v2f acc[COG][2];
#pragma unroll
    for (int co = 0; co < COG; ++co) {
        acc[co][0] = v2f{0.0f, 0.0f};
        acc[co][1] = v2f{0.0f, 0.0f};
    }

    for (int ci = 0; ci < CIN; ++ci) {
        // 4 halo rows 2ty2..2ty2+3 feed output rows 2ty2, 2ty2+1
        v2f xw[4][3];
#pragma unroll
        for (int r = 0; r < 4; ++r) {
            const float* row = &xs[ci][2 * ty2 + r][2 * tx];
            v2f p0 = *reinterpret_cast<const v2f*>(row);      // cols 2tx,2tx+1
            v2f p1 = *reinterpret_cast<const v2f*>(row + 2);  // cols 2tx+2,+3
            xw[r][0] = p0;
            xw[r][1] = v2f{p0.y, p1.x};
            xw[r][2] = p1;
        }

        const float* wc = w + (ci * COUT + cog) * 9;   // wave-uniform scalar
        const float* bc = bias + ci * COUT + cog;
#pragma unroll
        for (int co = 0; co < COG; ++co) {
            v2f s0 = v2f{0.0f, 0.0f};                  // out row 2ty2
            v2f s1 = v2f{0.0f, 0.0f};                  // out row 2ty2+1
#pragma unroll
            for (int k = 0; k < 9; ++k) {              // k ascending per pixel
                float wv = wc[co * 9 + k];
                v2f wvv = v2f{wv, wv};
                s0 = __builtin_elementwise_fma(xw[k / 3][k % 3],     wvv, s0);
                s1 = __builtin_elementwise_fma(xw[k / 3 + 1][k % 3], wvv, s1);
            }
            float bv = bc[co];
            v2f bvv = v2f{bv, bv};
            v2f y0 = s0 + bvv, y1 = s1 + bvv;          // bias: pk_add
            v2f t0 = y0 * v2f{QS, QS}, t1 = y1 * v2f{QS, QS};
            v2f q0, q1;
            q0.x = rintf(t0.x); q0.y = rintf(t0.y);    // half-even
            q1.x = rintf(t1.x); q1.y = rintf(t1.y);
            acc[co][0] = __builtin_elementwise_fma(q0, v2f{DQ, DQ}, acc[co][0]);
            acc[co][1] = __builtin_elementwise_fma(q1, v2f{DQ, DQ}, acc[co][1]);
        }
    }

    // ---- store: 2 rows x 2 cols per thread per co, b64 each ----
    float* ob = out + ((size_t)b * COUT + cog) * H_ * W_;
    const int oh = tile_y + 2 * ty2;
    const int ow = tile_x + 2 * tx;
#pragma unroll
    for (int co = 0; co < COG; ++co) {
        *reinterpret_cast<v2f*>(ob + co * H_ * W_ + oh * W_ + ow)       = acc[co][0];
        *reinterpret_cast<v2f*>(ob + co * H_ * W_ + (oh + 1) * W_ + ow) = acc[co][1];
    }
}

extern "C" void kernel_launch(void* const* d_in, const int* in_sizes, int n_in,
                              void* d_out, int out_size, void* d_ws, size_t ws_size,
                              hipStream_t stream)
{
    const float* x    = (const float*)d_in[0];
    const float* w    = (const float*)d_in[1];
    const float* bias = (const float*)d_in[2];
    float* out        = (float*)d_out;

    dim3 grid(W_ / TW, H_ / TH, B_);   // (7, 7, 8) = 392 blocks, all 32 co/block
    dim3 block(256);
    conv_quant_sum_kernel<<<grid, block, 0, stream>>>(x, w, bias, out);
}